// Round 15
// baseline (125.588 us; speedup 1.0000x reference)
//
#include <hip/hip_runtime.h>
#include <hip/hip_bf16.h>

typedef __attribute__((ext_vector_type(8))) short short8;
typedef __attribute__((ext_vector_type(4))) float f32x4;

static constexpr int MT = 32768;  // rows
static constexpr int KT = 256;    // contraction
static constexpr int CT = 4096;   // classes

// round-to-nearest-even float -> bf16 bits
__device__ __forceinline__ unsigned short f2b(float f) {
  unsigned int b = __float_as_uint(f);
  b += 0x7FFFu + ((b >> 16) & 1u);
  return (unsigned short)(b >> 16);
}

// Prepass (B only): B [KT][CT] fp32 -> Bt [CT][KT] bf16 (LDS-tiled transpose)
__global__ void __launch_bounds__(256) cvtB_kernel(const float* __restrict__ B,
                                                   unsigned short* __restrict__ Bt) {
  __shared__ unsigned short tile[32][33];
  int b = blockIdx.x, tid = threadIdx.x;
  int c0 = (b & 127) * 32, k0 = (b >> 7) * 32;
  int tx = tid & 31, ty0 = tid >> 5;
#pragma unroll
  for (int i = 0; i < 4; ++i) {
    int ty = ty0 + i * 8;
    tile[ty][tx] = f2b(B[(size_t)(k0 + ty) * CT + c0 + tx]);
  }
  __syncthreads();
#pragma unroll
  for (int i = 0; i < 4; ++i) {
    int cy = ty0 + i * 8;
    Bt[(size_t)(c0 + cy) * KT + k0 + tx] = tile[tx][cy];
  }
}

__device__ __forceinline__ void gload16(const void* g, void* l) {
  __builtin_amdgcn_global_load_lds(
      (const __attribute__((address_space(1))) void*)g,
      (__attribute__((address_space(3))) void*)l, 16, 0, 0);
}

// BM=128 x BN=256, BK=64, 8 waves (2x4, each 64x64) x 512 threads,
// 16 waves/CU. A is staged DIRECTLY from fp32 input: global->reg loads
// (issued first), convert to bf16 + swizzled ds_write while B's
// global_load_lds flies — conversion happens once per element during
// staging, NOT on the ds_read->MFMA path (r11's mistake). LDS chunk
// slots XOR-swizzled (slot = kchunk ^ (row&7)); B via pre-swizzled
// global source. Epilogue: 4 LDS-repack passes, NT stores
// 1KB-contiguous per wave instruction.
__global__ void __launch_bounds__(512, 4) gemm_kernel(const float* __restrict__ A,
                                                      const unsigned short* __restrict__ Btw,
                                                      float* __restrict__ O) {
  constexpr int BK = 64;
  // 48 KB: K-loop aliases as Al(16KB)+Bl(32KB); epilogue float eb[32][264].
  __shared__ __align__(16) char smem[48 * 1024];
  unsigned short* Al = (unsigned short*)smem;       // [128][64] bf16, swizzled
  unsigned short* Bl = (unsigned short*)(smem + 16384);
  float* eb = (float*)smem;

  int bid = blockIdx.x;
  // XCD-aware swizzle (4096 % 8 == 0, bijective).
  int wg = (bid & 7) * 512 + (bid >> 3);
  int tc = wg & 15;    // 16 col tiles of 256
  int tr = wg >> 4;    // 256 row tiles of 128
  int r0 = tr * 128, c0 = tc * 256;

  int tid = threadIdx.x;
  int lane = tid & 63, wid = tid >> 6;
  int wr = wid >> 2, wc = wid & 3;      // 2x4 waves, each 64 rows x 64 cols
  int l15 = lane & 15, l4 = lane >> 4;

  f32x4 acc[4][4] = {};  // acc[n][m], swapped-operand orientation

  for (int t = 0; t < KT / BK; ++t) {   // 4 K-tiles
    if (t) __syncthreads();
    // A: issue fp32 global->reg loads first (2 chunks of 8 floats/thread)
    f32x4 alo[2], ahi[2];
#pragma unroll
    for (int i = 0; i < 2; ++i) {
      int c = i * 512 + tid;            // chunk id 0..1023 (8 k-values each)
      const float* src = A + (size_t)(r0 + (c >> 3)) * KT + t * BK + (c & 7) * 8;
      alo[i] = *reinterpret_cast<const f32x4*>(src);
      ahi[i] = *reinterpret_cast<const f32x4*>(src + 4);
    }
    // B: async global_load_lds (4 chunks/thread), flies under A's latency.
    // SOURCE k-chunk pre-swizzled: slot s of row r holds k-chunk s^(r&7).
#pragma unroll
    for (int i = 0; i < 4; ++i) {
      int c = i * 512 + tid;            // chunk id 0..2047
      int sc = (c & 7) ^ ((c >> 3) & 7);
      gload16(Btw + (size_t)(c0 + (c >> 3)) * KT + t * BK + sc * 8,
              Bl + (i * 512 + (tid & ~63)) * 8);
    }
    // A: convert once + swizzled ds_write (compiler waits only on A loads)
#pragma unroll
    for (int i = 0; i < 2; ++i) {
      int c = i * 512 + tid;
      int row = c >> 3, slot = (c & 7) ^ (row & 7);
      short8 o;
#pragma unroll
      for (int j = 0; j < 4; ++j) {
        o[j] = (short)f2b(alo[i][j]);
        o[4 + j] = (short)f2b(ahi[i][j]);
      }
      *reinterpret_cast<short8*>(Al + row * BK + slot * 8) = o;
    }
    __syncthreads();  // drains gload_lds (vmcnt) + ds_writes (lgkmcnt)

#pragma unroll
    for (int ks = 0; ks < 2; ++ks) {
      short8 af[4], bf[4];
#pragma unroll
      for (int m = 0; m < 4; ++m) {
        int row = wr * 64 + m * 16 + l15;
        int slot = (ks * 4 + l4) ^ (l15 & 7);      // de-swizzle ((row&7)=l15&7)
        af[m] = *reinterpret_cast<const short8*>(Al + row * BK + slot * 8);
      }
#pragma unroll
      for (int n = 0; n < 4; ++n) {
        int row = wc * 64 + n * 16 + l15;
        int slot = (ks * 4 + l4) ^ (l15 & 7);
        bf[n] = *reinterpret_cast<const short8*>(Bl + row * BK + slot * 8);
      }
#pragma unroll
      for (int n = 0; n < 4; ++n)
#pragma unroll
        for (int m = 0; m < 4; ++m)
          // swapped operands: lane holds 4 consecutive C columns of one row
          acc[n][m] = __builtin_amdgcn_mfma_f32_16x16x32_bf16(bf[n], af[m], acc[n][m], 0, 0, 0);
    }
  }

  // Epilogue: 4 passes of 32 rows x 256 cols; NT rows are 1KB contiguous.
  const float s = 1.0f / 16.0f;
#pragma unroll
  for (int p = 0; p < 4; ++p) {
    __syncthreads();  // K-loop ds_reads / previous pass's eb reads done
    if (wr == (p >> 1)) {
#pragma unroll
      for (int mm = 0; mm < 2; ++mm) {
        int m = (p & 1) * 2 + mm;
#pragma unroll
        for (int n = 0; n < 4; ++n) {
          f32x4 v = acc[n][m];
          v[0] *= s; v[1] *= s; v[2] *= s; v[3] *= s;
          *reinterpret_cast<f32x4*>(
              &eb[(mm * 16 + l15) * 264 + wc * 64 + n * 16 + l4 * 4]) = v;
        }
      }
    }
    __syncthreads();
#pragma unroll
    for (int i = 0; i < 4; ++i) {
      int r = i * 8 + wid;                 // 0..31
      f32x4 v = *reinterpret_cast<const f32x4*>(&eb[r * 264 + lane * 4]);
      __builtin_nontemporal_store(v, reinterpret_cast<f32x4*>(
          O + (size_t)(r0 + p * 32 + r) * CT + c0 + lane * 4));  // 1KB/row
    }
  }
}

// Correct-but-slow insurance path if ws_size is too small for the bf16 copy.
__global__ void __launch_bounds__(256) naive_kernel(const float* __restrict__ A,
                                                    const float* __restrict__ B,
                                                    float* __restrict__ O) {
  size_t i = (size_t)blockIdx.x * 256 + threadIdx.x;
  int col = (int)(i & (size_t)(CT - 1));
  int row = (int)(i >> 12);
  float s = 0.f;
  for (int k = 0; k < KT; ++k)
    s += A[(size_t)row * KT + k] * B[(size_t)k * CT + col];
  O[i] = s * (1.0f / 16.0f);
}

extern "C" void kernel_launch(void* const* d_in, const int* in_sizes, int n_in,
                              void* d_out, int out_size, void* d_ws, size_t ws_size,
                              hipStream_t stream) {
  const float* A = (const float*)d_in[0];
  const float* B = (const float*)d_in[1];
  float* O = (float*)d_out;
  const size_t needB = (size_t)CT * KT * sizeof(unsigned short);  // 2 MiB
  if (ws_size >= needB) {
    unsigned short* Btw = (unsigned short*)d_ws;
    cvtB_kernel<<<1024, 256, 0, stream>>>(B, Btw);
    gemm_kernel<<<(MT / 128) * (CT / 256), 512, 0, stream>>>(A, Btw, O);
  } else {
    naive_kernel<<<(unsigned)((size_t)MT * CT / 256), 256, 0, stream>>>(A, B, O);
  }
}

// Round 16
// 118.847 us; speedup vs baseline: 1.0567x; 1.0567x over previous
//
#include <hip/hip_runtime.h>
#include <hip/hip_bf16.h>

typedef __attribute__((ext_vector_type(8))) short short8;
typedef __attribute__((ext_vector_type(4))) float f32x4;

static constexpr int MT = 32768;  // rows
static constexpr int KT = 256;    // contraction
static constexpr int CT = 4096;   // classes

// round-to-nearest-even float -> bf16 bits
__device__ __forceinline__ unsigned short f2b(float f) {
  unsigned int b = __float_as_uint(f);
  b += 0x7FFFu + ((b >> 16) & 1u);
  return (unsigned short)(b >> 16);
}

// Merged prepass: blocks [0,4096) convert A (8 floats/lane);
// blocks [4096,5120) transpose-convert B into Bt[CT][KT].
__global__ void __launch_bounds__(256) cvt_kernel(const float* __restrict__ A,
                                                  const float* __restrict__ B,
                                                  unsigned short* __restrict__ Abf,
                                                  unsigned short* __restrict__ Bt) {
  __shared__ unsigned short tile[32][33];
  int bid = blockIdx.x, tid = threadIdx.x;
  if (bid < 4096) {
    int i = bid * 256 + tid;
    const float4 v0 = reinterpret_cast<const float4*>(A)[2 * i];
    const float4 v1 = reinterpret_cast<const float4*>(A)[2 * i + 1];
    short8 o;
    o[0] = (short)f2b(v0.x); o[1] = (short)f2b(v0.y);
    o[2] = (short)f2b(v0.z); o[3] = (short)f2b(v0.w);
    o[4] = (short)f2b(v1.x); o[5] = (short)f2b(v1.y);
    o[6] = (short)f2b(v1.z); o[7] = (short)f2b(v1.w);
    reinterpret_cast<short8*>(Abf)[i] = o;
  } else {
    int b = bid - 4096;
    int c0 = (b & 127) * 32, k0 = (b >> 7) * 32;
    int tx = tid & 31, ty0 = tid >> 5;
#pragma unroll
    for (int i = 0; i < 4; ++i) {
      int ty = ty0 + i * 8;
      tile[ty][tx] = f2b(B[(size_t)(k0 + ty) * CT + c0 + tx]);
    }
    __syncthreads();
#pragma unroll
    for (int i = 0; i < 4; ++i) {
      int cy = ty0 + i * 8;
      Bt[(size_t)(c0 + cy) * KT + k0 + tx] = tile[tx][cy];
    }
  }
}

__device__ __forceinline__ void gload16(const void* g, void* l) {
  __builtin_amdgcn_global_load_lds(
      (const __attribute__((address_space(1))) void*)g,
      (__attribute__((address_space(3))) void*)l, 16, 0, 0);
}

// BM=128 x BN=256, BK=32 DOUBLE-BUFFERED with counted vmcnt (T3/T4):
// stage(t+1) -> vmcnt(3) -> barrier -> compute(t) -> barrier. Tile t's 3
// loads/thread were issued one full compute-phase earlier, so the counted
// wait is ~free; t+1's loads stay in flight across barriers (never drain
// to 0 mid-loop). 8 waves (2x4, each 64x64) x 512 threads, 16 waves/CU,
// 48 KB LDS (2 x (8KB A + 16KB B)). Chunk slots XOR-swizzled
// (slot = kchunk ^ ((row>>1)&3), conflict-free b128 on 64B rows) via
// pre-swizzled global source + swizzled ds_read. Epilogue: 4 LDS-repack
// passes, NT stores 1KB-contiguous per wave instruction.
__global__ void __launch_bounds__(512, 4) gemm_kernel(const unsigned short* __restrict__ Abf,
                                                      const unsigned short* __restrict__ Btw,
                                                      float* __restrict__ O) {
  constexpr int BK = 32, NT_ = KT / BK;  // 8 K-tiles
  __shared__ __align__(16) char smem[48 * 1024];
  unsigned short* Albuf[2] = {(unsigned short*)smem, (unsigned short*)(smem + 8192)};
  unsigned short* Blbuf[2] = {(unsigned short*)(smem + 16384), (unsigned short*)(smem + 32768)};
  float* eb = (float*)smem;

  int bid = blockIdx.x;
  // XCD-aware swizzle (4096 % 8 == 0, bijective). Per-XCD slice:
  // 32 row-panels (2MB A bf16) + B 2MB ~ L2.
  int wg = (bid & 7) * 512 + (bid >> 3);
  int tc = wg & 15;    // 16 col tiles of 256
  int tr = wg >> 4;    // 256 row tiles of 128
  int r0 = tr * 128, c0 = tc * 256;

  int tid = threadIdx.x;
  int lane = tid & 63, wid = tid >> 6;
  int wr = wid >> 2, wc = wid & 3;      // 2x4 waves, each 64 rows x 64 cols
  int l15 = lane & 15, l4 = lane >> 4;
  const int sw = l4 ^ ((l15 >> 1) & 3);  // de-swizzled chunk slot for reads

  f32x4 acc[4][4] = {};  // acc[n][m], swapped-operand orientation

  // stage one K-tile (BK=32): A 128x32 (1 chunk/thread) + B 256x32 (2/thread)
  auto stage = [&](int buf, int t) {
    {
      int c = tid;                                  // A chunk id 0..511
      int sc = (c & 3) ^ ((c >> 3) & 3);            // kchunk ^ ((row>>1)&3)
      gload16(Abf + (size_t)(r0 + (c >> 2)) * KT + t * BK + sc * 8,
              Albuf[buf] + (wid * 64) * 8);
    }
#pragma unroll
    for (int i = 0; i < 2; ++i) {
      int c = i * 512 + tid;                        // B chunk id 0..1023
      int sc = (c & 3) ^ ((c >> 3) & 3);
      gload16(Btw + (size_t)(c0 + (c >> 2)) * KT + t * BK + sc * 8,
              Blbuf[buf] + (i * 512 + wid * 64) * 8);
    }
  };

  stage(0, 0);  // prologue: 3 loads in flight
#pragma unroll
  for (int t = 0; t < NT_; ++t) {
    const int cur = t & 1;
    if (t + 1 < NT_) stage(cur ^ 1, t + 1);        // +3 loads (6 outstanding)
    if (t + 1 < NT_) asm volatile("s_waitcnt vmcnt(3)" ::: "memory");
    else             asm volatile("s_waitcnt vmcnt(0)" ::: "memory");
    __builtin_amdgcn_s_barrier();                   // tile t visible to all

    short8 af[4], bf[4];
#pragma unroll
    for (int m = 0; m < 4; ++m)
      af[m] = *reinterpret_cast<const short8*>(
          Albuf[cur] + (wr * 64 + m * 16 + l15) * BK + sw * 8);
#pragma unroll
    for (int n = 0; n < 4; ++n)
      bf[n] = *reinterpret_cast<const short8*>(
          Blbuf[cur] + (wc * 64 + n * 16 + l15) * BK + sw * 8);
#pragma unroll
    for (int n = 0; n < 4; ++n)
#pragma unroll
      for (int m = 0; m < 4; ++m)
        // swapped operands: lane holds 4 consecutive C columns of one row
        acc[n][m] = __builtin_amdgcn_mfma_f32_16x16x32_bf16(bf[n], af[m], acc[n][m], 0, 0, 0);

    asm volatile("s_waitcnt lgkmcnt(0)" ::: "memory");
    __builtin_amdgcn_s_barrier();                   // buf[cur] free for t+2
  }

  // Epilogue: 4 passes of 32 rows x 256 cols; NT rows are 1KB contiguous.
  const float s = 1.0f / 16.0f;
#pragma unroll
  for (int p = 0; p < 4; ++p) {
    __syncthreads();  // K-loop ds_reads / previous pass's eb reads done
    if (wr == (p >> 1)) {
#pragma unroll
      for (int mm = 0; mm < 2; ++mm) {
        int m = (p & 1) * 2 + mm;
#pragma unroll
        for (int n = 0; n < 4; ++n) {
          f32x4 v = acc[n][m];
          v[0] *= s; v[1] *= s; v[2] *= s; v[3] *= s;
          *reinterpret_cast<f32x4*>(
              &eb[(mm * 16 + l15) * 264 + wc * 64 + n * 16 + l4 * 4]) = v;
        }
      }
    }
    __syncthreads();
#pragma unroll
    for (int i = 0; i < 4; ++i) {
      int r = i * 8 + wid;                 // 0..31
      f32x4 v = *reinterpret_cast<const f32x4*>(&eb[r * 264 + lane * 4]);
      __builtin_nontemporal_store(v, reinterpret_cast<f32x4*>(
          O + (size_t)(r0 + p * 32 + r) * CT + c0 + lane * 4));  // 1KB/row
    }
  }
}

// Correct-but-slow insurance path if ws_size is too small for the bf16 copies.
__global__ void __launch_bounds__(256) naive_kernel(const float* __restrict__ A,
                                                    const float* __restrict__ B,
                                                    float* __restrict__ O) {
  size_t i = (size_t)blockIdx.x * 256 + threadIdx.x;
  int col = (int)(i & (size_t)(CT - 1));
  int row = (int)(i >> 12);
  float s = 0.f;
  for (int k = 0; k < KT; ++k)
    s += A[(size_t)row * KT + k] * B[(size_t)k * CT + col];
  O[i] = s * (1.0f / 16.0f);
}

extern "C" void kernel_launch(void* const* d_in, const int* in_sizes, int n_in,
                              void* d_out, int out_size, void* d_ws, size_t ws_size,
                              hipStream_t stream) {
  const float* A = (const float*)d_in[0];
  const float* B = (const float*)d_in[1];
  float* O = (float*)d_out;
  const size_t needA = (size_t)MT * KT * sizeof(unsigned short);  // 16 MiB
  const size_t needB = (size_t)CT * KT * sizeof(unsigned short);  //  2 MiB
  if (ws_size >= needA + needB) {
    unsigned short* Abf = (unsigned short*)d_ws;
    unsigned short* Btw = (unsigned short*)((char*)d_ws + needA);
    cvt_kernel<<<4096 + 1024, 256, 0, stream>>>(A, B, Abf, Btw);
    gemm_kernel<<<(MT / 128) * (CT / 256), 512, 0, stream>>>(Abf, Btw, O);
  } else {
    naive_kernel<<<(unsigned)((size_t)MT * CT / 256), 256, 0, stream>>>(A, B, O);
  }
}